// Round 11
// baseline (188.019 us; speedup 1.0000x reference)
//
#include <hip/hip_runtime.h>
#include <hip/hip_bf16.h>
#include <stdint.h>

#define DEV __device__ __forceinline__

typedef unsigned short u16;
typedef unsigned int   u32;
typedef __attribute__((ext_vector_type(8))) short bf16x8;   // 8 bf16 = 4 VGPRs
typedef __attribute__((ext_vector_type(4))) float f32x4;
typedef __attribute__((ext_vector_type(4))) u32   u32x4;
typedef __attribute__((ext_vector_type(2))) u32   u32x2;

// ---- numeric helpers -------------------------------------------------------
DEV u16 f2bf(float f) {            // RNE f32 -> bf16
  u32 u = __builtin_bit_cast(u32, f);
  u = (u + 0x7fffu + ((u >> 16) & 1u)) >> 16;
  return (u16)u;
}
DEV float bf2f(u16 h) { return __builtin_bit_cast(float, (u32)h << 16); }
DEV u32 pk2(float a, float b) {    // pack 2 f32 -> 2 bf16 in one u32 (RNE)
  u32 x = __builtin_bit_cast(u32, a), y = __builtin_bit_cast(u32, b);
  x = (x + 0x7fffu + ((x >> 16) & 1u)) >> 16;
  y = (y + 0x7fffu + ((y >> 16) & 1u)) >> 16;
  return x | (y << 16);
}
DEV u32 cvtpk(float lo, float hi) {  // 1-instr RNE pack
  u32 r;
  asm("v_cvt_pk_bf16_f32 %0, %1, %2" : "=v"(r) : "v"(lo), "v"(hi));
  return r;
}
DEV f32x4 mfma16(bf16x8 a, bf16x8 b, f32x4 c) {
  return __builtin_amdgcn_mfma_f32_16x16x32_bf16(a, b, c, 0, 0, 0);
}
DEV void gload16(const void* g, void* l) {   // global -> LDS direct, 16B/lane
  __builtin_amdgcn_global_load_lds(
      (const __attribute__((address_space(1))) void*)g,
      (__attribute__((address_space(3))) void*)l, 16, 0, 0);
}

// ---- problem constants -----------------------------------------------------
// B=2 T=2048 DIM=1024 HEADS=16 HEAD_DIM=64; tokens = 4096
// workspace layout (bytes):
//  XB      0         x as bf16            [4096][1024]
//  WQKVT   8388608   Wqkv^T bf16          [3072][1024]
//  WPROJT  14680064  Wproj^T bf16         [1024][1024]
//  QKV     16777216  qkv bf16             [4096][3072]
//  QR      41943040  roped*scale Q bf16   [32][2048][64]
//  KR      50331648  roped K bf16         [32][2048][64]
//  VT      58720256  V^T bf16 KEY-PERMUTED [32][64][2048]
//  AO      67108864  attn out bf16        [4096][1024]
//  SIN     75497472  f32 [2048][32]
//  COS     75759616  f32 [2048][32]
//  QCNT    76021760  u32[8] per-XCD queue counters (memset each launch)

// ---- prep kernels ----------------------------------------------------------
__global__ __launch_bounds__(256) void k_cvt_bf16(const float* __restrict__ in,
                                                  u16* __restrict__ out) {
  size_t i = ((size_t)blockIdx.x * 256 + threadIdx.x) * 8;
  float4 a = *(const float4*)(in + i);
  float4 b = *(const float4*)(in + i + 4);
  u32x4 o = { pk2(a.x, a.y), pk2(a.z, a.w), pk2(b.x, b.y), pk2(b.z, b.w) };
  *(u32x4*)(out + i) = o;
}

// W [1024][Ndim] f32 -> WT [Ndim][1024] bf16 (coalesced both sides via LDS)
__global__ __launch_bounds__(256) void k_transpose_cvt(const float* __restrict__ W,
                                                       u16* __restrict__ WT,
                                                       int Ndim) {
  int bk = blockIdx.x & 31;        // K/32 = 32
  int bn = blockIdx.x >> 5;
  int k0 = bk * 32, n0 = bn * 32;
  __shared__ float t[32][33];
  int tx = threadIdx.x & 31, ty = threadIdx.x >> 5; // ty 0..7
#pragma unroll
  for (int i = 0; i < 4; ++i)
    t[ty + 8 * i][tx] = W[(size_t)(k0 + ty + 8 * i) * Ndim + n0 + tx];
  __syncthreads();
#pragma unroll
  for (int i = 0; i < 4; ++i) {
    int n = ty + 8 * i;
    WT[(size_t)(n0 + n) * 1024 + k0 + tx] = f2bf(t[tx][n]);
  }
}

__global__ __launch_bounds__(256) void k_tables(const int* __restrict__ posp,
                                                float* __restrict__ sint,
                                                float* __restrict__ cost) {
  int i = blockIdx.x * 256 + threadIdx.x;   // 65536 = 2048*32
  int t = i >> 5, d = i & 31;
  float theta = exp2f(-(float)d * (13.2877123795494f / 32.0f));
  float ang = (float)(posp[0] + t) * theta;
  sint[i] = sinf(ang);
  cost[i] = cosf(ang);
}

// ---- GEMM: C[4096][N] = A[4096][1024] @ BT^T + bias ------------------------
// 128x128 tile, BK=64, 4 waves, mfma 16x16x32 bf16. global_load_lds width=16,
// linear LDS dest, XOR chunk swizzle c^(row&7) on the GLOBAL source (rule #21);
// reads use the same XOR -> <=2-way bank aliasing.
template <int N, bool OUTF32>
__global__ __launch_bounds__(256, 3) void k_gemm(const u16* __restrict__ A,
                                                 const u16* __restrict__ BT,
                                                 const float* __restrict__ bias,
                                                 void* __restrict__ Cout) {
  constexpr int K = 1024;
  int bm = blockIdx.x & 31;             // M/128 = 32
  int bn = blockIdx.x >> 5;
  int m0 = bm * 128, n0 = bn * 128;
  int tid = threadIdx.x, lane = tid & 63, w = tid >> 6;
  int g = lane >> 4, l15 = lane & 15;
  int wr = w >> 1, wc = w & 1;

  __shared__ u16 Alds[128 * 64];        // 16KB: row = 64 K-elems = 8 chunks
  __shared__ u16 Blds[128 * 64];

  f32x4 acc[4][4] = {};

  int rstg = lane >> 3;                 // 0..7
  int cswz = (lane & 7) ^ rstg;         // pre-swizzled source chunk

  const u16* Ag[4]; const u16* Bg[4]; char* Al[4]; char* Bl[4];
#pragma unroll
  for (int j = 0; j < 4; ++j) {
    int rb = j * 32 + w * 8;            // wave-uniform row base
    Ag[j] = A  + (size_t)(m0 + rb + rstg) * K + cswz * 8;
    Bg[j] = BT + (size_t)(n0 + rb + rstg) * K + cswz * 8;
    Al[j] = (char*)Alds + rb * 128;
    Bl[j] = (char*)Blds + rb * 128;
  }

  for (int k0 = 0; k0 < K; k0 += 64) {
#pragma unroll
    for (int j = 0; j < 4; ++j) {
      gload16(Ag[j] + k0, Al[j]);
      gload16(Bg[j] + k0, Bl[j]);
    }
    __syncthreads();                    // drains vmcnt (compiler-inserted)
#pragma unroll
    for (int kk = 0; kk < 2; ++kk) {
      bf16x8 af[4], bf_[4];
#pragma unroll
      for (int m = 0; m < 4; ++m) {
        int r = wr * 64 + m * 16 + l15;
        af[m] = *(const bf16x8*)((const char*)Alds + r * 128 +
                                 (((kk * 4 + g) ^ (r & 7)) << 4));
      }
#pragma unroll
      for (int n = 0; n < 4; ++n) {
        int r = wc * 64 + n * 16 + l15;
        bf_[n] = *(const bf16x8*)((const char*)Blds + r * 128 +
                                  (((kk * 4 + g) ^ (r & 7)) << 4));
      }
#pragma unroll
      for (int m = 0; m < 4; ++m)
#pragma unroll
        for (int n = 0; n < 4; ++n)
          acc[m][n] = mfma16(af[m], bf_[n], acc[m][n]);
    }
    __syncthreads();                    // reads done before next staging
  }

#pragma unroll
  for (int m = 0; m < 4; ++m) {
    int rowb = m0 + wr * 64 + m * 16 + 4 * g;
#pragma unroll
    for (int n = 0; n < 4; ++n) {
      int col = n0 + wc * 64 + n * 16 + l15;
      float bv = bias[col];
#pragma unroll
      for (int j = 0; j < 4; ++j) {
        float v = acc[m][n][j] + bv;
        if constexpr (OUTF32)
          ((float*)Cout)[(size_t)(rowb + j) * N + col] = v;
        else
          ((u16*)Cout)[(size_t)(rowb + j) * N + col] = f2bf(v);
      }
    }
  }
}

// ---- RoPE + head reshape + V transpose (key-permuted for PV b128 frags) ----
// VT key order within each 64-tile: key kk = 32*s2 + 16*b + 4*g + j stored at
// pos = 32*s2 + 8*g + 4*b + j, so each PV A-fragment (8 keys) is contiguous.
__global__ __launch_bounds__(256) void k_rope(const u16* __restrict__ qkv,
                                              const float* __restrict__ sint,
                                              const float* __restrict__ cost,
                                              u16* __restrict__ QR,
                                              u16* __restrict__ KR,
                                              u16* __restrict__ VT) {
  int bid = blockIdx.x;
  int bh = bid >> 5;                 // T/64 = 32 blocks per (b,h)
  int t0 = (bid & 31) * 64;
  int b = bh >> 4, h = bh & 15;
  int tid = threadIdx.x;

  int dp = tid & 31;
  int tt0 = tid >> 5;                 // 0..7
#pragma unroll
  for (int r = 0; r < 8; ++r) {
    int tl = r * 8 + tt0;
    int t = t0 + tl;
    int tok = b * 2048 + t;
    const u16* row = qkv + (size_t)tok * 3072;
    float sn = sint[t * 32 + dp], cs = cost[t * 32 + dp];

    u32 qq = *(const u32*)(row + h * 64 + 2 * dp);
    float x1 = bf2f((u16)qq), x2 = bf2f((u16)(qq >> 16));
    u16* qo = QR + ((size_t)bh * 2048 + t) * 64;
    qo[dp]      = f2bf(0.125f * (x1 * cs - x2 * sn));
    qo[dp + 32] = f2bf(0.125f * (x1 * sn + x2 * cs));

    u32 kk = *(const u32*)(row + 1024 + h * 64 + 2 * dp);
    x1 = bf2f((u16)kk); x2 = bf2f((u16)(kk >> 16));
    u16* ko = KR + ((size_t)bh * 2048 + t) * 64;
    ko[dp]      = f2bf(x1 * cs - x2 * sn);
    ko[dp + 32] = f2bf(x1 * sn + x2 * cs);
  }

  __shared__ u16 vld[64][72];
#pragma unroll
  for (int it = 0; it < 2; ++it) {
    int slot = it * 256 + tid;
    int tl = slot >> 3, ch = slot & 7;
    int tok = b * 2048 + t0 + tl;
    uint4 v = *(const uint4*)(qkv + (size_t)tok * 3072 + 2048 + h * 64 + ch * 8);
    *(uint4*)&vld[tl][ch * 8] = v;
  }
  __syncthreads();
#pragma unroll
  for (int it = 0; it < 2; ++it) {
    int slot = it * 256 + tid;
    int d = slot >> 3, tch = slot & 7;  // keys tch*8 .. tch*8+7
    u16 tmp[8];
#pragma unroll
    for (int i = 0; i < 8; ++i) tmp[i] = vld[tch * 8 + i][d];
    // perm: kk = tch*8+i -> pos = 32*s2 + 8*g + 4*b + j
    int s2 = tch >> 2, bb = (tch >> 1) & 1;
    int g0 = (2 * tch) & 3;            // i in [0,4)
    int g1 = (2 * tch + 1) & 3;        // i in [4,8)
    u16* vout = VT + ((size_t)bh * 64 + d) * 2048 + t0 + s2 * 32 + bb * 4;
    u32x2 lo = { (u32)tmp[0] | ((u32)tmp[1] << 16), (u32)tmp[2] | ((u32)tmp[3] << 16) };
    u32x2 hi = { (u32)tmp[4] | ((u32)tmp[5] << 16), (u32)tmp[6] | ((u32)tmp[7] << 16) };
    *(u32x2*)(vout + g0 * 8) = lo;
    *(u32x2*)(vout + g1 * 8) = hi;
  }
}

// ---- causal flash attention v9: per-XCD work queues ------------------------
// R9 proved dynamic balance, R10 proved global queues thrash L2 (in-flight
// window spans ~24 bh regardless of order). Fix: bind the queue to the cache.
// 8 queues, one per XCD; queue q owns bh {4q..4q+3} x 32 heavy-first 64q
// tiles (128 items) -> per-XCD working set 2MB <= 4MB L2. Workers read their
// XCD via s_getreg(HW_REG_XCC_ID) (block-uniform via LDS broadcast); when the
// home queue drains they STEAL from the next queue -> correct under any
// placement and even if XCC_ID misreads (locality-only hint). Engine = R9
// verbatim (16q/wave, VGPR 52, no spill at (256,3)): KVBLK=64 dbuf LDS via
// global_load_lds + source-side XOR swizzle, key-permuted single-b128 V
// frags (0 conflicts), defer-max, cvt_pk, per-lane partial l, setprio.
__global__ __launch_bounds__(256, 3) void k_attn(const u16* __restrict__ QR,
                                                 const u16* __restrict__ KR,
                                                 const u16* __restrict__ VT,
                                                 u16* __restrict__ AO,
                                                 u32* __restrict__ qcnt) {
  int tid = threadIdx.x;
  int w = tid >> 6, lane = tid & 63;
  int g = lane >> 4, l15 = lane & 15;
  int l7 = l15 & 7;

  __shared__ u16 Klds[2][64 * 64];   // 8KB/buf: [key][64 d], chunk-swizzled
  __shared__ u16 Vlds[2][64 * 64];   // 8KB/buf: [d][64 key perm], swizzled
  __shared__ u32 itemS;
  __shared__ u32 qselS;

  int kx0 = ((g ^ l7) << 4);
  int kx1 = (((4 + g) ^ l7) << 4);
  int rstg = lane >> 3;              // 0..7
  int cswz = (lane & 7) ^ rstg;      // pre-swizzled source chunk

  // hwreg(HW_REG_XCC_ID=20, offset=0, size=32) -> imm = 20 | (31<<11)
  if (tid == 0) qselS = __builtin_amdgcn_s_getreg(63508) & 7u;
  __syncthreads();
  int qsel = (int)qselS;             // uniform across block
  int scanned = 0;

  for (;;) {
    if (tid == 0) itemS = atomicAdd(&qcnt[qsel], 1u);
    __syncthreads();
    u32 item = itemS;
    __syncthreads();                 // guard itemS reuse before next write

    if (item >= 128u) {              // this queue drained: steal from next
      if (++scanned == 8) break;
      qsel = (qsel + 1) & 7;
      continue;
    }

    int tile = 31 - (int)(item >> 2);  // heavy-first within the queue
    int bh = qsel * 4 + (int)(item & 3);
    int nt = tile + 1;                 // 64-key tiles
    int b = bh >> 4, h = bh & 15;
    int q0 = tile * 64 + w * 16;       // wave's 16 q rows
    int qa = q0 + l15;

    const u16* Kg = KR + (size_t)bh * 2048 * 64;
    const u16* Vg = VT + (size_t)bh * 64 * 2048;

    const u16* Qr = QR + ((size_t)bh * 2048 + q0 + l15) * 64 + 8 * g;
    bf16x8 qf0 = *(const bf16x8*)(Qr);
    bf16x8 qf1 = *(const bf16x8*)(Qr + 32);

    f32x4 o[4] = {};
    float m = -1e30f, l = 0.f;

    auto stage = [&](int kt, int buf) {
#pragma unroll
      for (int j = 0; j < 2; ++j) {
        int rb = j * 32 + w * 8;
        int r = rb + rstg;
        gload16(Kg + (size_t)(kt * 64 + r) * 64 + cswz * 8, &Klds[buf][rb * 64]);
        gload16(Vg + (size_t)r * 2048 + kt * 64 + cswz * 8, &Vlds[buf][rb * 64]);
      }
    };

    stage(0, 0);
    __syncthreads();
    int cur = 0;

    for (int t = 0; t < nt; ++t) {
      if (t + 1 < nt) stage(t + 1, cur ^ 1);   // async prefetch next tile
      const char* Kb = (const char*)&Klds[cur][0];
      const char* Vb = (const char*)&Vlds[cur][0];

      // S^T = K.Q (64 keys x 16 q)
      bf16x8 kf0[4], kf1[4];
#pragma unroll
      for (int blk = 0; blk < 4; ++blk) {
        const char* kb = Kb + blk * 2048 + l15 * 128;
        kf0[blk] = *(const bf16x8*)(kb + kx0);
        kf1[blk] = *(const bf16x8*)(kb + kx1);
      }
      f32x4 sb[4];
      __builtin_amdgcn_s_setprio(1);
#pragma unroll
      for (int blk = 0; blk < 4; ++blk) {
        f32x4 z = { 0.f, 0.f, 0.f, 0.f };
        z = mfma16(kf0[blk], qf0, z);
        sb[blk] = mfma16(kf1[blk], qf1, z);
      }
      __builtin_amdgcn_s_setprio(0);

      if (t == nt - 1) {               // causal mask, final tile only
        int tkb = t * 64 + 4 * g;
#pragma unroll
        for (int blk = 0; blk < 4; ++blk)
#pragma unroll
          for (int j = 0; j < 4; ++j) {
            int tk = tkb + blk * 16 + j;
            if (tk > qa) sb[blk][j] = -1e30f;
          }
      }

      // online softmax: lane-local max; cross-lane + rescale only on trip
      float mx = fmaxf(fmaxf(fmaxf(sb[0][0], sb[0][1]), fmaxf(sb[0][2], sb[0][3])),
                       fmaxf(fmaxf(sb[1][0], sb[1][1]), fmaxf(sb[1][2], sb[1][3])));
      mx = fmaxf(mx, fmaxf(fmaxf(fmaxf(sb[2][0], sb[2][1]), fmaxf(sb[2][2], sb[2][3])),
                           fmaxf(fmaxf(sb[3][0], sb[3][1]), fmaxf(sb[3][2], sb[3][3]))));
      if (!__all(mx <= m + 8.0f)) {
        mx = fmaxf(mx, __shfl_xor(mx, 16));
        mx = fmaxf(mx, __shfl_xor(mx, 32));
        float mnew = fmaxf(m, mx);
        float a = __builtin_amdgcn_exp2f((m - mnew) * 1.44269504f);
        l *= a;
#pragma unroll
        for (int d = 0; d < 4; ++d) o[d] *= a;
        m = mnew;
      }
      float em = m * 1.44269504f;
      float p[4][4];
      float ps = 0.f;
#pragma unroll
      for (int blk = 0; blk < 4; ++blk)
#pragma unroll
        for (int j = 0; j < 4; ++j) {
          float pv = __builtin_amdgcn_exp2f(__builtin_fmaf(sb[blk][j], 1.44269504f, -em));
          p[blk][j] = pv;
          ps += pv;
        }
      l += ps;

      __builtin_amdgcn_s_setprio(1);
#pragma unroll
      for (int s2 = 0; s2 < 2; ++s2) {
        u32x4 pw = { cvtpk(p[2 * s2][0], p[2 * s2][1]),
                     cvtpk(p[2 * s2][2], p[2 * s2][3]),
                     cvtpk(p[2 * s2 + 1][0], p[2 * s2 + 1][1]),
                     cvtpk(p[2 * s2 + 1][2], p[2 * s2 + 1][3]) };
        bf16x8 pb = __builtin_bit_cast(bf16x8, pw);
        int vx = s2 ? kx1 : kx0;
#pragma unroll
        for (int dblk = 0; dblk < 4; ++dblk) {
          bf16x8 va = *(const bf16x8*)(Vb + dblk * 2048 + l15 * 128 + vx);
          o[dblk] = mfma16(va, pb, o[dblk]);
        }
      }
      __builtin_amdgcn_s_setprio(0);

      __syncthreads();
      cur ^= 1;
    }

    // epilogue (registers + global only)
    float lt = l + __shfl_xor(l, 16);
    lt += __shfl_xor(lt, 32);
    float inv = 1.0f / lt;
    u16* orow = AO + ((size_t)b * 2048 + q0 + l15) * 1024 + h * 64 + 4 * g;
#pragma unroll
    for (int dblk = 0; dblk < 4; ++dblk) {
      u32x2 ov = { cvtpk(o[dblk][0] * inv, o[dblk][1] * inv),
                   cvtpk(o[dblk][2] * inv, o[dblk][3] * inv) };
      *(u32x2*)(orow + dblk * 16) = ov;
    }
  }
}

// ---- launcher ---------------------------------------------------------------
extern "C" void kernel_launch(void* const* d_in, const int* in_sizes, int n_in,
                              void* d_out, int out_size, void* d_ws, size_t ws_size,
                              hipStream_t stream) {
  (void)in_sizes; (void)n_in; (void)out_size; (void)ws_size;
  const float* x     = (const float*)d_in[0];
  const float* Wqkv  = (const float*)d_in[1];
  const float* bqkv  = (const float*)d_in[2];
  const float* Wproj = (const float*)d_in[3];
  const float* bproj = (const float*)d_in[4];
  const int*   pos   = (const int*)d_in[5];

  char* ws = (char*)d_ws;
  u16*   XB     = (u16*)(ws + 0);
  u16*   WQKVT  = (u16*)(ws + 8388608);
  u16*   WPROJT = (u16*)(ws + 14680064);
  u16*   QKV    = (u16*)(ws + 16777216);
  u16*   QR     = (u16*)(ws + 41943040);
  u16*   KR     = (u16*)(ws + 50331648);
  u16*   VT     = (u16*)(ws + 58720256);
  u16*   AO     = (u16*)(ws + 67108864);
  float* SIN    = (float*)(ws + 75497472);
  float* COS    = (float*)(ws + 75759616);
  u32*   QCNT   = (u32*)(ws + 76021760);

  hipMemsetAsync(QCNT, 0, 32, stream);  // zero the 8 per-XCD queue counters

  k_cvt_bf16<<<2048, 256, 0, stream>>>(x, XB);
  k_transpose_cvt<<<32 * 96, 256, 0, stream>>>(Wqkv, WQKVT, 3072);
  k_transpose_cvt<<<32 * 32, 256, 0, stream>>>(Wproj, WPROJT, 1024);
  k_tables<<<256, 256, 0, stream>>>(pos, SIN, COS);
  k_gemm<3072, false><<<32 * 24, 256, 0, stream>>>(XB, WQKVT, bqkv, QKV);
  k_rope<<<32 * 32, 256, 0, stream>>>(QKV, SIN, COS, QR, KR, VT);
  k_attn<<<768, 256, 0, stream>>>(QR, KR, VT, AO, QCNT);
  k_gemm<1024, true><<<32 * 8, 256, 0, stream>>>(AO, WPROJT, bproj, d_out);
}

// Round 12
// 125.604 us; speedup vs baseline: 1.4969x; 1.4969x over previous
//
#include <hip/hip_runtime.h>
#include <hip/hip_bf16.h>
#include <stdint.h>

#define DEV __device__ __forceinline__

typedef unsigned short u16;
typedef unsigned int   u32;
typedef __attribute__((ext_vector_type(8))) short bf16x8;   // 8 bf16 = 4 VGPRs
typedef __attribute__((ext_vector_type(4))) float f32x4;
typedef __attribute__((ext_vector_type(4))) u32   u32x4;
typedef __attribute__((ext_vector_type(2))) u32   u32x2;

// ---- numeric helpers -------------------------------------------------------
DEV u16 f2bf(float f) {            // RNE f32 -> bf16
  u32 u = __builtin_bit_cast(u32, f);
  u = (u + 0x7fffu + ((u >> 16) & 1u)) >> 16;
  return (u16)u;
}
DEV float bf2f(u16 h) { return __builtin_bit_cast(float, (u32)h << 16); }
DEV u32 pk2(float a, float b) {    // pack 2 f32 -> 2 bf16 in one u32 (RNE)
  u32 x = __builtin_bit_cast(u32, a), y = __builtin_bit_cast(u32, b);
  x = (x + 0x7fffu + ((x >> 16) & 1u)) >> 16;
  y = (y + 0x7fffu + ((y >> 16) & 1u)) >> 16;
  return x | (y << 16);
}
DEV u32 cvtpk(float lo, float hi) {  // 1-instr RNE pack (same semantics as pk2)
  u32 r;
  asm("v_cvt_pk_bf16_f32 %0, %1, %2" : "=v"(r) : "v"(lo), "v"(hi));
  return r;
}
DEV f32x4 mfma16(bf16x8 a, bf16x8 b, f32x4 c) {
  return __builtin_amdgcn_mfma_f32_16x16x32_bf16(a, b, c, 0, 0, 0);
}
DEV void gload16(const void* g, void* l) {   // global -> LDS direct, 16B/lane
  __builtin_amdgcn_global_load_lds(
      (const __attribute__((address_space(1))) void*)g,
      (__attribute__((address_space(3))) void*)l, 16, 0, 0);
}

// ---- problem constants -----------------------------------------------------
// B=2 T=2048 DIM=1024 HEADS=16 HEAD_DIM=64; tokens = 4096
// workspace layout (bytes):
//  XB      0         x as bf16            [4096][1024]
//  WQKVT   8388608   Wqkv^T bf16          [3072][1024]
//  WPROJT  14680064  Wproj^T bf16         [1024][1024]
//  QKV     16777216  qkv bf16             [4096][3072]
//  QR      41943040  roped*scale Q bf16   [32][2048][64]
//  KR      50331648  roped K bf16         [32][2048][64]
//  VT      58720256  V^T bf16             [32][64][2048]
//  AO      67108864  attn out bf16        [4096][1024]
//  SIN     75497472  f32 [2048][32]
//  COS     75759616  f32 [2048][32]

// ---- prep kernels ----------------------------------------------------------
__global__ __launch_bounds__(256) void k_cvt_bf16(const float* __restrict__ in,
                                                  u16* __restrict__ out) {
  size_t i = ((size_t)blockIdx.x * 256 + threadIdx.x) * 8;
  float4 a = *(const float4*)(in + i);
  float4 b = *(const float4*)(in + i + 4);
  u32x4 o = { pk2(a.x, a.y), pk2(a.z, a.w), pk2(b.x, b.y), pk2(b.z, b.w) };
  *(u32x4*)(out + i) = o;
}

// W [1024][Ndim] f32 -> WT [Ndim][1024] bf16 (coalesced both sides via LDS)
__global__ __launch_bounds__(256) void k_transpose_cvt(const float* __restrict__ W,
                                                       u16* __restrict__ WT,
                                                       int Ndim) {
  int bk = blockIdx.x & 31;        // K/32 = 32
  int bn = blockIdx.x >> 5;
  int k0 = bk * 32, n0 = bn * 32;
  __shared__ float t[32][33];
  int tx = threadIdx.x & 31, ty = threadIdx.x >> 5; // ty 0..7
#pragma unroll
  for (int i = 0; i < 4; ++i)
    t[ty + 8 * i][tx] = W[(size_t)(k0 + ty + 8 * i) * Ndim + n0 + tx];
  __syncthreads();
#pragma unroll
  for (int i = 0; i < 4; ++i) {
    int n = ty + 8 * i;
    WT[(size_t)(n0 + n) * 1024 + k0 + tx] = f2bf(t[tx][n]);
  }
}

__global__ __launch_bounds__(256) void k_tables(const int* __restrict__ posp,
                                                float* __restrict__ sint,
                                                float* __restrict__ cost) {
  int i = blockIdx.x * 256 + threadIdx.x;   // 65536 = 2048*32
  int t = i >> 5, d = i & 31;
  float theta = exp2f(-(float)d * (13.2877123795494f / 32.0f));
  float ang = (float)(posp[0] + t) * theta;
  sint[i] = sinf(ang);
  cost[i] = cosf(ang);
}

// ---- GEMM: C[4096][N] = A[4096][1024] @ BT^T + bias ------------------------
// m97 single-barrier structure (NEW this round): double-buffered LDS, stage
// next K-step via global_load_lds BEFORE computing current, ONE barrier per
// step (the sync's vmcnt drain covers the staged loads). Ladder-verified
// +69% over the old stage;sync;compute;sync form (m93->m97, 517->874 TF).
// 128x128 tile, BK=32, 4 waves (2x2 of 64x64), mfma 16x16x32 bf16. Swizzle:
// source chunk c^((row>>1)&3) on global addr (rule #21), same XOR on reads.
template <int N, bool OUTF32>
__global__ __launch_bounds__(256, 3) void k_gemm(const u16* __restrict__ A,
                                                 const u16* __restrict__ BT,
                                                 const float* __restrict__ bias,
                                                 void* __restrict__ Cout) {
  constexpr int K = 1024;
  int bm = blockIdx.x & 31;             // M/128 = 32
  int bn = blockIdx.x >> 5;
  int m0 = bm * 128, n0 = bn * 128;
  int tid = threadIdx.x, lane = tid & 63, w = tid >> 6;
  int g = lane >> 4, l15 = lane & 15;
  int wr = w >> 1, wc = w & 1;

  __shared__ u16 Alds[2][128 * 32];     // 8KB per buf
  __shared__ u16 Blds[2][128 * 32];

  f32x4 acc[4][4] = {};

  int rowW = w * 16 + (lane >> 2);
  int cSrc = (lane & 3) ^ ((lane >> 3) & 3);
  const u16* Ag0 = A  + (size_t)(m0 + rowW) * K + cSrc * 8;
  const u16* Ag1 = A  + (size_t)(m0 + 64 + rowW) * K + cSrc * 8;
  const u16* Bg0 = BT + (size_t)(n0 + rowW) * K + cSrc * 8;
  const u16* Bg1 = BT + (size_t)(n0 + 64 + rowW) * K + cSrc * 8;

  auto stage = [&](int k0, int buf) {
    gload16(Ag0 + k0, (char*)&Alds[buf][0] + w * 1024);
    gload16(Ag1 + k0, (char*)&Alds[buf][0] + 4096 + w * 1024);
    gload16(Bg0 + k0, (char*)&Blds[buf][0] + w * 1024);
    gload16(Bg1 + k0, (char*)&Blds[buf][0] + 4096 + w * 1024);
  };

  stage(0, 0);
  __syncthreads();
  int cur = 0;

#pragma unroll 1
  for (int it = 0; it < 32; ++it) {
    if (it + 1 < 32) stage((it + 1) * 32, cur ^ 1);  // loads fly under compute
    const char* Ab = (const char*)&Alds[cur][0];
    const char* Bb = (const char*)&Blds[cur][0];
    bf16x8 af[4], bf_[4];
#pragma unroll
    for (int m = 0; m < 4; ++m) {
      int r = wr * 64 + m * 16 + l15;
      af[m] = *(const bf16x8*)(Ab + r * 64 + ((g ^ ((r >> 1) & 3)) << 4));
    }
#pragma unroll
    for (int n = 0; n < 4; ++n) {
      int r = wc * 64 + n * 16 + l15;
      bf_[n] = *(const bf16x8*)(Bb + r * 64 + ((g ^ ((r >> 1) & 3)) << 4));
    }
#pragma unroll
    for (int m = 0; m < 4; ++m)
#pragma unroll
      for (int n = 0; n < 4; ++n)
        acc[m][n] = mfma16(af[m], bf_[n], acc[m][n]);
    __syncthreads();                    // single barrier: drains loads + reads
    cur ^= 1;
  }

#pragma unroll
  for (int m = 0; m < 4; ++m) {
    int rowb = m0 + wr * 64 + m * 16 + 4 * g;
#pragma unroll
    for (int n = 0; n < 4; ++n) {
      int col = n0 + wc * 64 + n * 16 + l15;
      float bv = bias[col];
#pragma unroll
      for (int j = 0; j < 4; ++j) {
        float v = acc[m][n][j] + bv;
        if constexpr (OUTF32)
          ((float*)Cout)[(size_t)(rowb + j) * N + col] = v;
        else
          ((u16*)Cout)[(size_t)(rowb + j) * N + col] = f2bf(v);
      }
    }
  }
}

// ---- RoPE + head reshape + V transpose (R5 verbatim, plain VT) -------------
__global__ __launch_bounds__(256) void k_rope(const u16* __restrict__ qkv,
                                              const float* __restrict__ sint,
                                              const float* __restrict__ cost,
                                              u16* __restrict__ QR,
                                              u16* __restrict__ KR,
                                              u16* __restrict__ VT) {
  int bid = blockIdx.x;
  int bh = bid >> 5;                 // T/64 = 32 blocks per (b,h)
  int t0 = (bid & 31) * 64;
  int b = bh >> 4, h = bh & 15;
  int tid = threadIdx.x;

  int dp = tid & 31;
  int tt0 = tid >> 5;                 // 0..7
#pragma unroll
  for (int r = 0; r < 8; ++r) {
    int tl = r * 8 + tt0;
    int t = t0 + tl;
    int tok = b * 2048 + t;
    const u16* row = qkv + (size_t)tok * 3072;
    float sn = sint[t * 32 + dp], cs = cost[t * 32 + dp];

    u32 qq = *(const u32*)(row + h * 64 + 2 * dp);
    float x1 = bf2f((u16)qq), x2 = bf2f((u16)(qq >> 16));
    u16* qo = QR + ((size_t)bh * 2048 + t) * 64;
    qo[dp]      = f2bf(0.125f * (x1 * cs - x2 * sn));
    qo[dp + 32] = f2bf(0.125f * (x1 * sn + x2 * cs));

    u32 kk = *(const u32*)(row + 1024 + h * 64 + 2 * dp);
    x1 = bf2f((u16)kk); x2 = bf2f((u16)(kk >> 16));
    u16* ko = KR + ((size_t)bh * 2048 + t) * 64;
    ko[dp]      = f2bf(x1 * cs - x2 * sn);
    ko[dp + 32] = f2bf(x1 * sn + x2 * cs);
  }

  __shared__ u16 vld[64][72];
#pragma unroll
  for (int it = 0; it < 2; ++it) {
    int slot = it * 256 + tid;
    int tl = slot >> 3, ch = slot & 7;
    int tok = b * 2048 + t0 + tl;
    uint4 v = *(const uint4*)(qkv + (size_t)tok * 3072 + 2048 + h * 64 + ch * 8);
    *(uint4*)&vld[tl][ch * 8] = v;
  }
  __syncthreads();
#pragma unroll
  for (int it = 0; it < 2; ++it) {
    int slot = it * 256 + tid;
    int d = slot >> 3, tch = slot & 7;
    u16 tmp[8];
#pragma unroll
    for (int i = 0; i < 8; ++i) tmp[i] = vld[tch * 8 + i][d];
    u32x4 o = { (u32)tmp[0] | ((u32)tmp[1] << 16), (u32)tmp[2] | ((u32)tmp[3] << 16),
                (u32)tmp[4] | ((u32)tmp[5] << 16), (u32)tmp[6] | ((u32)tmp[7] << 16) };
    *(u32x4*)(VT + ((size_t)bh * 64 + d) * 2048 + t0 + tch * 8) = o;
  }
}

// ---- causal flash attention (R5 verbatim — proven 46.0 us) -----------------
// 1024 blocks = 32 bh x 32 q-tiles (64 rows); 4 waves, one 16-row subtile per
// wave. KVBLK=64 double-buffered LDS (32KB) staged via global_load_lds with
// source-side XOR swizzle. Heavy-first dispatch + 4 blocks/CU residency.
// defer-max (T13), cvt_pk pack, per-lane partial l, setprio (T5).
__global__ __launch_bounds__(256, 4) void k_attn(const u16* __restrict__ QR,
                                                 const u16* __restrict__ KR,
                                                 const u16* __restrict__ VT,
                                                 u16* __restrict__ AO) {
  int tid = threadIdx.x;
  int w = tid >> 6, lane = tid & 63;
  int g = lane >> 4, l15 = lane & 15;
  int l7 = l15 & 7, g2 = g >> 1;

  int idx = blockIdx.x;
  int tt = 31 - (idx >> 5);          // q-tile 31..0 (heavy first)
  int bh = idx & 31;                 // bh mod 8 = XCD slot -> 4 bh per XCD
  int nt = tt + 1;                   // 64-key tiles to process
  int b = bh >> 4, h = bh & 15;
  int q0 = tt * 64 + w * 16;         // wave's 16-row subtile
  int qa = q0 + l15;

  const u16* Kg = KR + (size_t)bh * 2048 * 64;
  const u16* Vg = VT + (size_t)bh * 64 * 2048;

  __shared__ u16 Klds[2][64 * 64];   // 8KB/buf: [key][64 d], swizzled
  __shared__ u16 Vlds[2][64 * 64];   // 8KB/buf: [d][64 key], swizzled

  const u16* Qr = QR + ((size_t)bh * 2048 + q0 + l15) * 64 + 8 * g;
  bf16x8 qf0 = *(const bf16x8*)(Qr);
  bf16x8 qf1 = *(const bf16x8*)(Qr + 32);

  f32x4 o[4] = {};
  float m = -1e30f, l = 0.f;

  // hoisted LDS read constants
  int kx0 = ((g ^ l7) << 4);                 // K frag chunk offsets (bytes)
  int kx1 = (((4 + g) ^ l7) << 4);
  int vx0 = ((g2 ^ l7) << 4);                // V chunks s2=0: {g2, 2+g2}
  int vx1 = (((2 + g2) ^ l7) << 4);
  int vx2 = (((4 + g2) ^ l7) << 4);          // s2=1: {4+g2, 6+g2}
  int vx3 = (((6 + g2) ^ l7) << 4);
  int vbase = l15 * 128 + ((g & 1) << 3);

  // staging: 256 threads cover 64 rows x 8 chunks in 2 issues (K and V each)
  int rstg = lane >> 3;                      // 0..7
  int cswz = (lane & 7) ^ rstg;              // pre-swizzled source chunk

  auto stage = [&](int kt, int buf) {
#pragma unroll
    for (int j = 0; j < 2; ++j) {
      int r = j * 32 + w * 8 + rstg;
      gload16(Kg + (size_t)(kt * 64 + r) * 64 + cswz * 8,
              &Klds[buf][(j * 32 + w * 8) * 64]);
      gload16(Vg + (size_t)r * 2048 + kt * 64 + cswz * 8,
              &Vlds[buf][(j * 32 + w * 8) * 64]);
    }
  };

  stage(0, 0);
  __syncthreads();
  int cur = 0;

  for (int t = 0; t < nt; ++t) {
    if (t + 1 < nt) stage(t + 1, cur ^ 1);   // async prefetch next tile
    const char* Kb = (const char*)&Klds[cur][0];
    const char* Vb = (const char*)&Vlds[cur][0];

    // S^T = K.Q (64 keys x 16 q)
    f32x4 sb[4];
    __builtin_amdgcn_s_setprio(1);
#pragma unroll
    for (int blk = 0; blk < 4; ++blk) {
      const char* kb = Kb + blk * 2048 + l15 * 128;
      bf16x8 k0 = *(const bf16x8*)(kb + kx0);
      bf16x8 k1 = *(const bf16x8*)(kb + kx1);
      f32x4 z = { 0.f, 0.f, 0.f, 0.f };
      z = mfma16(k0, qf0, z);
      sb[blk] = mfma16(k1, qf1, z);
    }
    __builtin_amdgcn_s_setprio(0);

    if (t == nt - 1) {               // causal mask, final tile only
      int tk0 = t * 64;
#pragma unroll
      for (int blk = 0; blk < 4; ++blk)
#pragma unroll
        for (int j = 0; j < 4; ++j) {
          int tk = tk0 + blk * 16 + 4 * g + j;
          if (tk > qa) sb[blk][j] = -1e30f;
        }
    }

    // online softmax (defer-max) + PV
    float mx = fmaxf(fmaxf(fmaxf(sb[0][0], sb[0][1]), fmaxf(sb[0][2], sb[0][3])),
                     fmaxf(fmaxf(sb[1][0], sb[1][1]), fmaxf(sb[1][2], sb[1][3])));
    mx = fmaxf(mx, fmaxf(fmaxf(fmaxf(sb[2][0], sb[2][1]), fmaxf(sb[2][2], sb[2][3])),
                         fmaxf(fmaxf(sb[3][0], sb[3][1]), fmaxf(sb[3][2], sb[3][3]))));
    mx = fmaxf(mx, __shfl_xor(mx, 16));
    mx = fmaxf(mx, __shfl_xor(mx, 32));
    if (!__all(mx <= m + 8.0f)) {
      float mnew = fmaxf(m, mx);
      float a = __builtin_amdgcn_exp2f((m - mnew) * 1.44269504f);
      l *= a;
#pragma unroll
      for (int d = 0; d < 4; ++d) o[d] *= a;
      m = mnew;
    }
    float em = m * 1.44269504f;
    float p[4][4];
    float ps = 0.f;
#pragma unroll
    for (int blk = 0; blk < 4; ++blk)
#pragma unroll
      for (int j = 0; j < 4; ++j) {
        float pv = __builtin_amdgcn_exp2f(__builtin_fmaf(sb[blk][j], 1.44269504f, -em));
        p[blk][j] = pv;
        ps += pv;
      }
    l += ps;

    __builtin_amdgcn_s_setprio(1);
#pragma unroll
    for (int s2 = 0; s2 < 2; ++s2) {
      u32x4 pw = { cvtpk(p[2 * s2][0], p[2 * s2][1]),
                   cvtpk(p[2 * s2][2], p[2 * s2][3]),
                   cvtpk(p[2 * s2 + 1][0], p[2 * s2 + 1][1]),
                   cvtpk(p[2 * s2 + 1][2], p[2 * s2 + 1][3]) };
      bf16x8 pb = __builtin_bit_cast(bf16x8, pw);
      int cl = s2 ? vx2 : vx0;
      int ch = s2 ? vx3 : vx1;
#pragma unroll
      for (int dblk = 0; dblk < 4; ++dblk) {
        uint2 lo = *(const uint2*)(Vb + vbase + dblk * 2048 + cl);
        uint2 hi = *(const uint2*)(Vb + vbase + dblk * 2048 + ch);
        bf16x8 va = __builtin_bit_cast(bf16x8, u32x4{ lo.x, lo.y, hi.x, hi.y });
        o[dblk] = mfma16(va, pb, o[dblk]);
      }
    }
    __builtin_amdgcn_s_setprio(0);

    __syncthreads();
    cur ^= 1;
  }

  float lt = l + __shfl_xor(l, 16);
  lt += __shfl_xor(lt, 32);
  float inv = 1.0f / lt;
  u16* orow = AO + ((size_t)b * 2048 + q0 + l15) * 1024 + h * 64 + 4 * g;
#pragma unroll
  for (int dblk = 0; dblk < 4; ++dblk) {
    u32x2 ov = { cvtpk(o[dblk][0] * inv, o[dblk][1] * inv),
                 cvtpk(o[dblk][2] * inv, o[dblk][3] * inv) };
    *(u32x2*)(orow + dblk * 16) = ov;
  }
}

// ---- launcher ---------------------------------------------------------------
extern "C" void kernel_launch(void* const* d_in, const int* in_sizes, int n_in,
                              void* d_out, int out_size, void* d_ws, size_t ws_size,
                              hipStream_t stream) {
  (void)in_sizes; (void)n_in; (void)out_size; (void)ws_size;
  const float* x     = (const float*)d_in[0];
  const float* Wqkv  = (const float*)d_in[1];
  const float* bqkv  = (const float*)d_in[2];
  const float* Wproj = (const float*)d_in[3];
  const float* bproj = (const float*)d_in[4];
  const int*   pos   = (const int*)d_in[5];

  char* ws = (char*)d_ws;
  u16*   XB     = (u16*)(ws + 0);
  u16*   WQKVT  = (u16*)(ws + 8388608);
  u16*   WPROJT = (u16*)(ws + 14680064);
  u16*   QKV    = (u16*)(ws + 16777216);
  u16*   QR     = (u16*)(ws + 41943040);
  u16*   KR     = (u16*)(ws + 50331648);
  u16*   VT     = (u16*)(ws + 58720256);
  u16*   AO     = (u16*)(ws + 67108864);
  float* SIN    = (float*)(ws + 75497472);
  float* COS    = (float*)(ws + 75759616);

  k_cvt_bf16<<<2048, 256, 0, stream>>>(x, XB);
  k_transpose_cvt<<<32 * 96, 256, 0, stream>>>(Wqkv, WQKVT, 3072);
  k_transpose_cvt<<<32 * 32, 256, 0, stream>>>(Wproj, WPROJT, 1024);
  k_tables<<<256, 256, 0, stream>>>(pos, SIN, COS);
  k_gemm<3072, false><<<32 * 24, 256, 0, stream>>>(XB, WQKVT, bqkv, QKV);
  k_rope<<<32 * 32, 256, 0, stream>>>(QKV, SIN, COS, QR, KR, VT);
  k_attn<<<1024, 256, 0, stream>>>(QR, KR, VT, AO);
  k_gemm<1024, true><<<32 * 8, 256, 0, stream>>>(AO, WPROJT, bproj, d_out);
}

// Round 13
// 113.010 us; speedup vs baseline: 1.6637x; 1.1114x over previous
//
#include <hip/hip_runtime.h>
#include <hip/hip_bf16.h>
#include <stdint.h>

#define DEV __device__ __forceinline__

typedef unsigned short u16;
typedef unsigned int   u32;
typedef __attribute__((ext_vector_type(8))) short bf16x8;   // 8 bf16 = 4 VGPRs
typedef __attribute__((ext_vector_type(4))) float f32x4;
typedef __attribute__((ext_vector_type(4))) u32   u32x4;
typedef __attribute__((ext_vector_type(2))) u32   u32x2;

// ---- numeric helpers -------------------------------------------------------
DEV u16 f2bf(float f) {            // RNE f32 -> bf16
  u32 u = __builtin_bit_cast(u32, f);
  u = (u + 0x7fffu + ((u >> 16) & 1u)) >> 16;
  return (u16)u;
}
DEV float bf2f(u16 h) { return __builtin_bit_cast(float, (u32)h << 16); }
DEV u32 pk2(float a, float b) {    // pack 2 f32 -> 2 bf16 in one u32 (RNE)
  u32 x = __builtin_bit_cast(u32, a), y = __builtin_bit_cast(u32, b);
  x = (x + 0x7fffu + ((x >> 16) & 1u)) >> 16;
  y = (y + 0x7fffu + ((y >> 16) & 1u)) >> 16;
  return x | (y << 16);
}
DEV u32 cvtpk(float lo, float hi) {  // 1-instr RNE pack (same semantics as pk2)
  u32 r;
  asm("v_cvt_pk_bf16_f32 %0, %1, %2" : "=v"(r) : "v"(lo), "v"(hi));
  return r;
}
DEV f32x4 mfma16(bf16x8 a, bf16x8 b, f32x4 c) {
  return __builtin_amdgcn_mfma_f32_16x16x32_bf16(a, b, c, 0, 0, 0);
}
DEV void gload16(const void* g, void* l) {   // global -> LDS direct, 16B/lane
  __builtin_amdgcn_global_load_lds(
      (const __attribute__((address_space(1))) void*)g,
      (__attribute__((address_space(3))) void*)l, 16, 0, 0);
}

// ---- problem constants -----------------------------------------------------
// B=2 T=2048 DIM=1024 HEADS=16 HEAD_DIM=64; tokens = 4096
// workspace layout (bytes):
//  XB      0         x as bf16            [4096][1024]
//  WQKVT   8388608   Wqkv^T bf16          [3072][1024]
//  WPROJT  14680064  Wproj^T bf16         [1024][1024]
//  (QKV slot unused since R13 — rope fused into GEMM epilogue)
//  QR      41943040  roped*scale Q bf16   [32][2048][64]
//  KR      50331648  roped K bf16         [32][2048][64]
//  VT      58720256  V^T bf16             [32][64][2048]
//  AO      67108864  attn out bf16        [4096][1024]
//  SIN     75497472  f32 [2048][32]
//  COS     75759616  f32 [2048][32]

// ---- merged prep kernel ----------------------------------------------------
// blocks [0,2048): x f32 -> XB bf16
// blocks [2048,5120): Wqkv [1024][3072] -> WQKVT [3072][1024] bf16
// blocks [5120,6144): Wproj [1024][1024] -> WPROJT [1024][1024] bf16
// blocks [6144,6400): rope sin/cos tables
__global__ __launch_bounds__(256) void k_prep(const float* __restrict__ x,
                                              u16* __restrict__ XB,
                                              const float* __restrict__ Wqkv,
                                              u16* __restrict__ WQKVT,
                                              const float* __restrict__ Wproj,
                                              u16* __restrict__ WPROJT,
                                              const int* __restrict__ posp,
                                              float* __restrict__ sint,
                                              float* __restrict__ cost) {
  __shared__ float t[32][33];
  int bid = blockIdx.x;
  int tid = threadIdx.x;

  if (bid < 2048) {                        // ---- cvt x -> bf16
    size_t i = ((size_t)bid * 256 + tid) * 8;
    float4 a = *(const float4*)(x + i);
    float4 b = *(const float4*)(x + i + 4);
    u32x4 o = { pk2(a.x, a.y), pk2(a.z, a.w), pk2(b.x, b.y), pk2(b.z, b.w) };
    *(u32x4*)(XB + i) = o;
    return;
  }
  if (bid < 6144) {                        // ---- W transpose+cvt
    const float* W; u16* WT; int Ndim, idx;
    if (bid < 5120) { W = Wqkv;  WT = WQKVT;  Ndim = 3072; idx = bid - 2048; }
    else            { W = Wproj; WT = WPROJT; Ndim = 1024; idx = bid - 5120; }
    int bk = idx & 31;
    int bn = idx >> 5;
    int k0 = bk * 32, n0 = bn * 32;
    int tx = tid & 31, ty = tid >> 5;      // ty 0..7
#pragma unroll
    for (int i = 0; i < 4; ++i)
      t[ty + 8 * i][tx] = W[(size_t)(k0 + ty + 8 * i) * Ndim + n0 + tx];
    __syncthreads();
#pragma unroll
    for (int i = 0; i < 4; ++i) {
      int n = ty + 8 * i;
      WT[(size_t)(n0 + n) * 1024 + k0 + tx] = f2bf(t[tx][n]);
    }
    return;
  }
  // ---- rope tables
  int i = (bid - 6144) * 256 + tid;        // 65536 = 2048*32
  int tt = i >> 5, d = i & 31;
  float theta = exp2f(-(float)d * (13.2877123795494f / 32.0f));
  float ang = (float)(posp[0] + tt) * theta;
  sint[i] = sinf(ang);
  cost[i] = cosf(ang);
}

// ---- QKV GEMM with fused RoPE / V-transpose epilogue -----------------------
// Main loop = R12's m97 single-barrier structure (verified). Epilogue writes
// QR (roped, *0.125), KR (roped), VT (transposed) directly from the f32
// accumulators — k_rope and the QKV intermediate are gone. RoPE pairs are
// adjacent columns = adjacent lanes (l15 parity): one __shfl_xor(v,1) gives
// the partner value. Tiles: bn 0..7 = Q, 8..15 = K, 16..23 = V (tile never
// straddles head or batch boundaries: 128 | 2048 rows, 64 | 128 cols).
__global__ __launch_bounds__(256, 3) void k_gemm_qkv(const u16* __restrict__ A,
                                                     const u16* __restrict__ BT,
                                                     const float* __restrict__ bias,
                                                     u16* __restrict__ QR,
                                                     u16* __restrict__ KR,
                                                     u16* __restrict__ VT,
                                                     const float* __restrict__ sint,
                                                     const float* __restrict__ cost) {
  constexpr int K = 1024;
  int bm = blockIdx.x & 31;             // M/128 = 32
  int bn = blockIdx.x >> 5;             // 0..23
  int m0 = bm * 128, n0 = bn * 128;
  int tid = threadIdx.x, lane = tid & 63, w = tid >> 6;
  int g = lane >> 4, l15 = lane & 15;
  int wr = w >> 1, wc = w & 1;

  __shared__ u16 Alds[2][128 * 32];     // 8KB per buf
  __shared__ u16 Blds[2][128 * 32];

  f32x4 acc[4][4] = {};

  int rowW = w * 16 + (lane >> 2);
  int cSrc = (lane & 3) ^ ((lane >> 3) & 3);
  const u16* Ag0 = A  + (size_t)(m0 + rowW) * K + cSrc * 8;
  const u16* Ag1 = A  + (size_t)(m0 + 64 + rowW) * K + cSrc * 8;
  const u16* Bg0 = BT + (size_t)(n0 + rowW) * K + cSrc * 8;
  const u16* Bg1 = BT + (size_t)(n0 + 64 + rowW) * K + cSrc * 8;

  auto stage = [&](int k0, int buf) {
    gload16(Ag0 + k0, (char*)&Alds[buf][0] + w * 1024);
    gload16(Ag1 + k0, (char*)&Alds[buf][0] + 4096 + w * 1024);
    gload16(Bg0 + k0, (char*)&Blds[buf][0] + w * 1024);
    gload16(Bg1 + k0, (char*)&Blds[buf][0] + 4096 + w * 1024);
  };

  stage(0, 0);
  __syncthreads();
  int cur = 0;

#pragma unroll 1
  for (int it = 0; it < 32; ++it) {
    if (it + 1 < 32) stage((it + 1) * 32, cur ^ 1);  // loads fly under compute
    const char* Ab = (const char*)&Alds[cur][0];
    const char* Bb = (const char*)&Blds[cur][0];
    bf16x8 af[4], bf_[4];
#pragma unroll
    for (int m = 0; m < 4; ++m) {
      int r = wr * 64 + m * 16 + l15;
      af[m] = *(const bf16x8*)(Ab + r * 64 + ((g ^ ((r >> 1) & 3)) << 4));
    }
#pragma unroll
    for (int n = 0; n < 4; ++n) {
      int r = wc * 64 + n * 16 + l15;
      bf_[n] = *(const bf16x8*)(Bb + r * 64 + ((g ^ ((r >> 1) & 3)) << 4));
    }
#pragma unroll
    for (int m = 0; m < 4; ++m)
#pragma unroll
      for (int n = 0; n < 4; ++n)
        acc[m][n] = mfma16(af[m], bf_[n], acc[m][n]);
    __syncthreads();                    // single barrier: drains loads + reads
    cur ^= 1;
  }

  int bq = m0 >> 11;                    // batch index (uniform per tile)

  if (bn >= 16) {
    // ---- V: transposed store into VT[bh][d][t], 4 tokens packed per store
#pragma unroll
    for (int m = 0; m < 4; ++m) {
      int rowb = m0 + wr * 64 + m * 16 + 4 * g;
      int tt = rowb & 2047;
#pragma unroll
      for (int n = 0; n < 4; ++n) {
        int colv = n0 + wc * 64 + n * 16 + l15 - 2048;
        float bv = bias[colv + 2048];
        int h = colv >> 6, d = colv & 63;
        int bh = bq * 16 + h;
        u32x2 o = { pk2(acc[m][n][0] + bv, acc[m][n][1] + bv),
                    pk2(acc[m][n][2] + bv, acc[m][n][3] + bv) };
        *(u32x2*)(VT + ((size_t)(bh * 64 + d)) * 2048 + tt) = o;
      }
    }
  } else {
    // ---- Q/K: fused RoPE. even f: out[dp] = x1*cs - x2*sn ; odd f:
    // out[32+dp] = x1*sn + x2*cs ; partner value via __shfl_xor(v,1).
    bool isQ = (bn < 8);
    u16* OUT = isQ ? QR : KR;
    int cofs = isQ ? 0 : 1024;
    float sc = isQ ? 0.125f : 1.0f;
#pragma unroll
    for (int m = 0; m < 4; ++m) {
      int rowb = m0 + wr * 64 + m * 16 + 4 * g;
#pragma unroll
      for (int n = 0; n < 4; ++n) {
        int col = n0 + wc * 64 + n * 16 + l15 - cofs;
        float bv = bias[col + cofs];
        int h = col >> 6, f = col & 63;
        int bh = bq * 16 + h;
        int dp = f >> 1;
        int outf = (f & 1) ? (32 + dp) : dp;
#pragma unroll
        for (int j = 0; j < 4; ++j) {
          int tt = (rowb + j) & 2047;
          float v = acc[m][n][j] + bv;
          float pv = __shfl_xor(v, 1);
          float sn = sint[tt * 32 + dp], cs = cost[tt * 32 + dp];
          float out = (f & 1) ? (pv * sn + v * cs) : (v * cs - pv * sn);
          OUT[((size_t)(bh * 2048 + tt)) * 64 + outf] = f2bf(sc * out);
        }
      }
    }
  }
}

// ---- proj GEMM: C[4096][1024] f32 = AO @ WPROJT^T + bias -------------------
// (R12 structure, unchanged)
__global__ __launch_bounds__(256, 3) void k_gemm_proj(const u16* __restrict__ A,
                                                      const u16* __restrict__ BT,
                                                      const float* __restrict__ bias,
                                                      float* __restrict__ Cout) {
  constexpr int K = 1024, N = 1024;
  int bm = blockIdx.x & 31;
  int bn = blockIdx.x >> 5;
  int m0 = bm * 128, n0 = bn * 128;
  int tid = threadIdx.x, lane = tid & 63, w = tid >> 6;
  int g = lane >> 4, l15 = lane & 15;
  int wr = w >> 1, wc = w & 1;

  __shared__ u16 Alds[2][128 * 32];
  __shared__ u16 Blds[2][128 * 32];

  f32x4 acc[4][4] = {};

  int rowW = w * 16 + (lane >> 2);
  int cSrc = (lane & 3) ^ ((lane >> 3) & 3);
  const u16* Ag0 = A  + (size_t)(m0 + rowW) * K + cSrc * 8;
  const u16* Ag1 = A  + (size_t)(m0 + 64 + rowW) * K + cSrc * 8;
  const u16* Bg0 = BT + (size_t)(n0 + rowW) * K + cSrc * 8;
  const u16* Bg1 = BT + (size_t)(n0 + 64 + rowW) * K + cSrc * 8;

  auto stage = [&](int k0, int buf) {
    gload16(Ag0 + k0, (char*)&Alds[buf][0] + w * 1024);
    gload16(Ag1 + k0, (char*)&Alds[buf][0] + 4096 + w * 1024);
    gload16(Bg0 + k0, (char*)&Blds[buf][0] + w * 1024);
    gload16(Bg1 + k0, (char*)&Blds[buf][0] + 4096 + w * 1024);
  };

  stage(0, 0);
  __syncthreads();
  int cur = 0;

#pragma unroll 1
  for (int it = 0; it < 32; ++it) {
    if (it + 1 < 32) stage((it + 1) * 32, cur ^ 1);
    const char* Ab = (const char*)&Alds[cur][0];
    const char* Bb = (const char*)&Blds[cur][0];
    bf16x8 af[4], bf_[4];
#pragma unroll
    for (int m = 0; m < 4; ++m) {
      int r = wr * 64 + m * 16 + l15;
      af[m] = *(const bf16x8*)(Ab + r * 64 + ((g ^ ((r >> 1) & 3)) << 4));
    }
#pragma unroll
    for (int n = 0; n < 4; ++n) {
      int r = wc * 64 + n * 16 + l15;
      bf_[n] = *(const bf16x8*)(Bb + r * 64 + ((g ^ ((r >> 1) & 3)) << 4));
    }
#pragma unroll
    for (int m = 0; m < 4; ++m)
#pragma unroll
      for (int n = 0; n < 4; ++n)
        acc[m][n] = mfma16(af[m], bf_[n], acc[m][n]);
    __syncthreads();
    cur ^= 1;
  }

#pragma unroll
  for (int m = 0; m < 4; ++m) {
    int rowb = m0 + wr * 64 + m * 16 + 4 * g;
#pragma unroll
    for (int n = 0; n < 4; ++n) {
      int col = n0 + wc * 64 + n * 16 + l15;
      float bv = bias[col];
#pragma unroll
      for (int j = 0; j < 4; ++j)
        Cout[(size_t)(rowb + j) * N + col] = acc[m][n][j] + bv;
    }
  }
}

// ---- causal flash attention (R5 verbatim — proven 46.0 us) -----------------
__global__ __launch_bounds__(256, 4) void k_attn(const u16* __restrict__ QR,
                                                 const u16* __restrict__ KR,
                                                 const u16* __restrict__ VT,
                                                 u16* __restrict__ AO) {
  int tid = threadIdx.x;
  int w = tid >> 6, lane = tid & 63;
  int g = lane >> 4, l15 = lane & 15;
  int l7 = l15 & 7, g2 = g >> 1;

  int idx = blockIdx.x;
  int tt = 31 - (idx >> 5);          // q-tile 31..0 (heavy first)
  int bh = idx & 31;                 // bh mod 8 = XCD slot -> 4 bh per XCD
  int nt = tt + 1;                   // 64-key tiles to process
  int b = bh >> 4, h = bh & 15;
  int q0 = tt * 64 + w * 16;         // wave's 16-row subtile
  int qa = q0 + l15;

  const u16* Kg = KR + (size_t)bh * 2048 * 64;
  const u16* Vg = VT + (size_t)bh * 64 * 2048;

  __shared__ u16 Klds[2][64 * 64];   // 8KB/buf: [key][64 d], swizzled
  __shared__ u16 Vlds[2][64 * 64];   // 8KB/buf: [d][64 key], swizzled

  const u16* Qr = QR + ((size_t)bh * 2048 + q0 + l15) * 64 + 8 * g;
  bf16x8 qf0 = *(const bf16x8*)(Qr);
  bf16x8 qf1 = *(const bf16x8*)(Qr + 32);

  f32x4 o[4] = {};
  float m = -1e30f, l = 0.f;

  // hoisted LDS read constants
  int kx0 = ((g ^ l7) << 4);                 // K frag chunk offsets (bytes)
  int kx1 = (((4 + g) ^ l7) << 4);
  int vx0 = ((g2 ^ l7) << 4);                // V chunks s2=0: {g2, 2+g2}
  int vx1 = (((2 + g2) ^ l7) << 4);
  int vx2 = (((4 + g2) ^ l7) << 4);          // s2=1: {4+g2, 6+g2}
  int vx3 = (((6 + g2) ^ l7) << 4);
  int vbase = l15 * 128 + ((g & 1) << 3);

  // staging: 256 threads cover 64 rows x 8 chunks in 2 issues (K and V each)
  int rstg = lane >> 3;                      // 0..7
  int cswz = (lane & 7) ^ rstg;              // pre-swizzled source chunk

  auto stage = [&](int kt, int buf) {
#pragma unroll
    for (int j = 0; j < 2; ++j) {
      int r = j * 32 + w * 8 + rstg;
      gload16(Kg + (size_t)(kt * 64 + r) * 64 + cswz * 8,
              &Klds[buf][(j * 32 + w * 8) * 64]);
      gload16(Vg + (size_t)r * 2048 + kt * 64 + cswz * 8,
              &Vlds[buf][(j * 32 + w * 8) * 64]);
    }
  };

  stage(0, 0);
  __syncthreads();
  int cur = 0;

  for (int t = 0; t < nt; ++t) {
    if (t + 1 < nt) stage(t + 1, cur ^ 1);   // async prefetch next tile
    const char* Kb = (const char*)&Klds[cur][0];
    const char* Vb = (const char*)&Vlds[cur][0];

    // S^T = K.Q (64 keys x 16 q)
    f32x4 sb[4];
    __builtin_amdgcn_s_setprio(1);
#pragma unroll
    for (int blk = 0; blk < 4; ++blk) {
      const char* kb = Kb + blk * 2048 + l15 * 128;
      bf16x8 k0 = *(const bf16x8*)(kb + kx0);
      bf16x8 k1 = *(const bf16x8*)(kb + kx1);
      f32x4 z = { 0.f, 0.f, 0.f, 0.f };
      z = mfma16(k0, qf0, z);
      sb[blk] = mfma16(k1, qf1, z);
    }
    __builtin_amdgcn_s_setprio(0);

    if (t == nt - 1) {               // causal mask, final tile only
      int tk0 = t * 64;
#pragma unroll
      for (int blk = 0; blk < 4; ++blk)
#pragma unroll
        for (int j = 0; j < 4; ++j) {
          int tk = tk0 + blk * 16 + 4 * g + j;
          if (tk > qa) sb[blk][j] = -1e30f;
        }
    }

    // online softmax (defer-max) + PV
    float mx = fmaxf(fmaxf(fmaxf(sb[0][0], sb[0][1]), fmaxf(sb[0][2], sb[0][3])),
                     fmaxf(fmaxf(sb[1][0], sb[1][1]), fmaxf(sb[1][2], sb[1][3])));
    mx = fmaxf(mx, fmaxf(fmaxf(fmaxf(sb[2][0], sb[2][1]), fmaxf(sb[2][2], sb[2][3])),
                         fmaxf(fmaxf(sb[3][0], sb[3][1]), fmaxf(sb[3][2], sb[3][3]))));
    mx = fmaxf(mx, __shfl_xor(mx, 16));
    mx = fmaxf(mx, __shfl_xor(mx, 32));
    if (!__all(mx <= m + 8.0f)) {
      float mnew = fmaxf(m, mx);
      float a = __builtin_amdgcn_exp2f((m - mnew) * 1.44269504f);
      l *= a;
#pragma unroll
      for (int d = 0; d < 4; ++d) o[d] *= a;
      m = mnew;
    }
    float em = m * 1.44269504f;
    float p[4][4];
    float ps = 0.f;
#pragma unroll
    for (int blk = 0; blk < 4; ++blk)
#pragma unroll
      for (int j = 0; j < 4; ++j) {
        float pv = __builtin_amdgcn_exp2f(__builtin_fmaf(sb[blk][j], 1.44269504f, -em));
        p[blk][j] = pv;
        ps += pv;
      }
    l += ps;

    __builtin_amdgcn_s_setprio(1);
#pragma unroll
    for (int s2 = 0; s2 < 2; ++s2) {
      u32x4 pw = { cvtpk(p[2 * s2][0], p[2 * s2][1]),
                   cvtpk(p[2 * s2][2], p[2 * s2][3]),
                   cvtpk(p[2 * s2 + 1][0], p[2 * s2 + 1][1]),
                   cvtpk(p[2 * s2 + 1][2], p[2 * s2 + 1][3]) };
      bf16x8 pb = __builtin_bit_cast(bf16x8, pw);
      int cl = s2 ? vx2 : vx0;
      int ch = s2 ? vx3 : vx1;
#pragma unroll
      for (int dblk = 0; dblk < 4; ++dblk) {
        uint2 lo = *(const uint2*)(Vb + vbase + dblk * 2048 + cl);
        uint2 hi = *(const uint2*)(Vb + vbase + dblk * 2048 + ch);
        bf16x8 va = __builtin_bit_cast(bf16x8, u32x4{ lo.x, lo.y, hi.x, hi.y });
        o[dblk] = mfma16(va, pb, o[dblk]);
      }
    }
    __builtin_amdgcn_s_setprio(0);

    __syncthreads();
    cur ^= 1;
  }

  float lt = l + __shfl_xor(l, 16);
  lt += __shfl_xor(lt, 32);
  float inv = 1.0f / lt;
  u16* orow = AO + ((size_t)b * 2048 + q0 + l15) * 1024 + h * 64 + 4 * g;
#pragma unroll
  for (int dblk = 0; dblk < 4; ++dblk) {
    u32x2 ov = { cvtpk(o[dblk][0] * inv, o[dblk][1] * inv),
                 cvtpk(o[dblk][2] * inv, o[dblk][3] * inv) };
    *(u32x2*)(orow + dblk * 16) = ov;
  }
}

// ---- launcher ---------------------------------------------------------------
extern "C" void kernel_launch(void* const* d_in, const int* in_sizes, int n_in,
                              void* d_out, int out_size, void* d_ws, size_t ws_size,
                              hipStream_t stream) {
  (void)in_sizes; (void)n_in; (void)out_size; (void)ws_size;
  const float* x     = (const float*)d_in[0];
  const float* Wqkv  = (const float*)d_in[1];
  const float* bqkv  = (const float*)d_in[2];
  const float* Wproj = (const float*)d_in[3];
  const float* bproj = (const float*)d_in[4];
  const int*   pos   = (const int*)d_in[5];

  char* ws = (char*)d_ws;
  u16*   XB     = (u16*)(ws + 0);
  u16*   WQKVT  = (u16*)(ws + 8388608);
  u16*   WPROJT = (u16*)(ws + 14680064);
  u16*   QR     = (u16*)(ws + 41943040);
  u16*   KR     = (u16*)(ws + 50331648);
  u16*   VT     = (u16*)(ws + 58720256);
  u16*   AO     = (u16*)(ws + 67108864);
  float* SIN    = (float*)(ws + 75497472);
  float* COS    = (float*)(ws + 75759616);

  k_prep<<<6400, 256, 0, stream>>>(x, XB, Wqkv, WQKVT, Wproj, WPROJT, pos, SIN, COS);
  k_gemm_qkv<<<32 * 24, 256, 0, stream>>>(XB, WQKVT, bqkv, QR, KR, VT, SIN, COS);
  k_attn<<<1024, 256, 0, stream>>>(QR, KR, VT, AO);
  k_gemm_proj<<<32 * 8, 256, 0, stream>>>(AO, WPROJT, bproj, (float*)d_out);
}